// Round 3
// baseline (722.348 us; speedup 1.0000x reference)
//
#include <hip/hip_runtime.h>

typedef unsigned short u16;
typedef unsigned int   u32;
typedef unsigned long long u64;
typedef __attribute__((ext_vector_type(8))) __bf16 bf16x8;
typedef __attribute__((ext_vector_type(4))) float  f32x4;

#define BB   16
#define CH   256
#define HW   2304
#define SEQ  2048
#define EMB  256
#define CTXD 128
#define OUT0 9437184   // 16*256*2304, float offset of att region in d_out
#define NQT  72        // HW/32
#define SLOTF 65536    // floats per att slot (32*2048)
#define NMASKW 1179648u // 16*2304*2048/64

#define MFMA(a,b,c) __builtin_amdgcn_mfma_f32_16x16x32_bf16(a,b,c,0,0,0)

__device__ __forceinline__ u16 f2bf(float f){
  u32 u = __builtin_bit_cast(u32, f);
  u += 0x7fffu + ((u >> 16) & 1u);
  return (u16)(u >> 16);
}
__device__ __forceinline__ float bf2f(u32 us){ return __builtin_bit_cast(float, us << 16); }

__device__ __forceinline__ bf16x8 ld16(const u16* p){
  uint4 q = *reinterpret_cast<const uint4*>(p);
  return __builtin_bit_cast(bf16x8, q);
}
__device__ __forceinline__ bf16x8 mk8(float a0,float a1,float a2,float a3,
                                      float a4,float a5,float a6,float a7){
  uint4 q;
  q.x = (u32)f2bf(a0) | ((u32)f2bf(a1) << 16);
  q.y = (u32)f2bf(a2) | ((u32)f2bf(a3) << 16);
  q.z = (u32)f2bf(a4) | ((u32)f2bf(a5) << 16);
  q.w = (u32)f2bf(a6) | ((u32)f2bf(a7) << 16);
  return __builtin_bit_cast(bf16x8, q);
}

// ---------------- K0: weight prep -------------------------------------------
__global__ __launch_bounds__(256) void k_prep(
    const float* __restrict__ Wq, const float* __restrict__ W_in,
    const float* __restrict__ b_in, const float* __restrict__ bq,
    const float* __restrict__ Wk, const float* __restrict__ Wv,
    const float* __restrict__ Wout,
    u16* __restrict__ WqinBf, u16* __restrict__ WkBf, u16* __restrict__ WvBf,
    u16* __restrict__ WoutBf, float* __restrict__ bq_eff)
{
  int blk = blockIdx.x, t = threadIdx.x;
  if (blk < 256) {
    int e = blk, c = t;
    float s = 0.f;
    for (int f = 0; f < 256; f++) s += Wq[e*256+f] * W_in[f*256+c];
    WqinBf[e*256+c] = f2bf(s);
    if (t == 0) {
      float bb = bq[e];
      for (int f = 0; f < 256; f++) bb += Wq[e*256+f] * b_in[f];
      bq_eff[e] = bb;
    }
  } else {
    u32 flat = (u32)(blk - 256) * 256 + t;
    for (u32 idx = flat; idx < 131072u; idx += 16384u) {
      if (idx < 32768u)       WkBf[idx]          = f2bf(Wk[idx]);
      else if (idx < 65536u)  WvBf[idx - 32768u] = f2bf(Wv[idx - 32768u]);
      else                    WoutBf[idx - 65536u] = f2bf(Wout[idx - 65536u]);
    }
  }
}

// ---------------- K0b: mask bit-pack ----------------------------------------
// mb[w] bit l = (mask[w*64+l] != 0); word w covers 64 consecutive j of row w/32... (flat)
__global__ __launch_bounds__(256) void k_maskpack(
    const int* __restrict__ mask, u64* __restrict__ mb)
{
  u32 wid = ((u32)blockIdx.x * 256u + (u32)threadIdx.x) >> 6;
  u32 lane = threadIdx.x & 63;
  u32 nwv = ((u32)gridDim.x * 256u) >> 6;
  for (u32 w = wid; w < NMASKW; w += nwv) {
    int m = mask[(size_t)w * 64 + lane];
    u64 bm = __ballot(m != 0);
    if (lane == 0) mb[w] = bm;
  }
}

// ---------------- K1: Q projection ------------------------------------------
__global__ __launch_bounds__(256) void k_qproj(
    const float* __restrict__ x, const u16* __restrict__ WqinBf,
    const float* __restrict__ bq_eff, u16* __restrict__ Qbf)
{
  int b = blockIdx.y, ibase = blockIdx.x * 64;
  int t = threadIdx.x, wv = t >> 6, lane = t & 63, g4 = lane >> 4, r16 = lane & 15;
  int e0 = wv * 64;
  f32x4 acc[4][4] = {};
  #pragma unroll 2
  for (int kk = 0; kk < 8; kk++) {
    bf16x8 a[4];
    #pragma unroll
    for (int m = 0; m < 4; m++)
      a[m] = ld16(WqinBf + (size_t)(e0 + m*16 + r16) * 256 + kk*32 + g4*8);
    bf16x8 bb[4];
    #pragma unroll
    for (int n = 0; n < 4; n++) {
      const float* xp = x + ((size_t)b*CH + kk*32 + g4*8) * HW + ibase + n*16 + r16;
      bb[n] = mk8(xp[0], xp[HW], xp[2*HW], xp[3*HW], xp[4*HW], xp[5*HW], xp[6*HW], xp[7*HW]);
    }
    #pragma unroll
    for (int m = 0; m < 4; m++)
      #pragma unroll
      for (int n = 0; n < 4; n++)
        acc[m][n] = MFMA(a[m], bb[n], acc[m][n]);
  }
  #pragma unroll
  for (int m = 0; m < 4; m++) {
    int e = e0 + m*16 + g4*4;
    float b0 = bq_eff[e], b1 = bq_eff[e+1], b2 = bq_eff[e+2], b3 = bq_eff[e+3];
    #pragma unroll
    for (int n = 0; n < 4; n++) {
      int i = ibase + n*16 + r16;
      u32 lo = (u32)f2bf(acc[m][n][0] + b0) | ((u32)f2bf(acc[m][n][1] + b1) << 16);
      u32 hi = (u32)f2bf(acc[m][n][2] + b2) | ((u32)f2bf(acc[m][n][3] + b3) << 16);
      *(uint2*)(Qbf + ((size_t)b*HW + i) * EMB + e) = make_uint2(lo, hi);
    }
  }
}

// ---------------- K2: K & V projections -------------------------------------
__global__ __launch_bounds__(512) void k_kvproj(
    const float* __restrict__ ctx, const u16* __restrict__ WkBf, const u16* __restrict__ WvBf,
    const float* __restrict__ bk, const float* __restrict__ bv,
    u16* __restrict__ Kbf, u16* __restrict__ Vtb)
{
  int b = blockIdx.y, sbase = blockIdx.x * 64;
  int t = threadIdx.x, wv = t >> 6, lane = t & 63, g4 = lane >> 4, r16 = lane & 15;
  bool isV = wv >= 4;
  int e0 = (wv & 3) * 64;
  const u16* Wsel = isV ? WvBf : WkBf;
  f32x4 acc[4][4] = {};
  #pragma unroll
  for (int kk = 0; kk < 4; kk++) {
    bf16x8 a[4];
    #pragma unroll
    for (int m = 0; m < 4; m++)
      a[m] = ld16(Wsel + (size_t)(e0 + m*16 + r16) * 128 + kk*32 + g4*8);
    bf16x8 bb[4];
    #pragma unroll
    for (int n = 0; n < 4; n++) {
      const float* cp = ctx + ((size_t)b*SEQ + sbase + n*16 + r16) * CTXD + kk*32 + g4*8;
      float4 lo = *(const float4*)cp;
      float4 hi = *(const float4*)(cp + 4);
      bb[n] = mk8(lo.x, lo.y, lo.z, lo.w, hi.x, hi.y, hi.z, hi.w);
    }
    #pragma unroll
    for (int m = 0; m < 4; m++)
      #pragma unroll
      for (int n = 0; n < 4; n++)
        acc[m][n] = MFMA(a[m], bb[n], acc[m][n]);
  }
  if (!isV) {
    #pragma unroll
    for (int m = 0; m < 4; m++) {
      int e = e0 + m*16 + g4*4;
      float b0 = bk[e], b1 = bk[e+1], b2 = bk[e+2], b3 = bk[e+3];
      #pragma unroll
      for (int n = 0; n < 4; n++) {
        int s = sbase + n*16 + r16;
        u32 lo = (u32)f2bf(acc[m][n][0] + b0) | ((u32)f2bf(acc[m][n][1] + b1) << 16);
        u32 hi = (u32)f2bf(acc[m][n][2] + b2) | ((u32)f2bf(acc[m][n][3] + b3) << 16);
        *(uint2*)(Kbf + ((size_t)b*SEQ + s) * EMB + e) = make_uint2(lo, hi);
      }
    }
  } else {
    #pragma unroll
    for (int m = 0; m < 4; m++) {
      #pragma unroll
      for (int r = 0; r < 4; r++) {
        int e = e0 + m*16 + g4*4 + r;
        float bvv = bv[e];
        #pragma unroll
        for (int n = 0; n < 4; n++) {
          int s = sbase + n*16 + r16;
          Vtb[((size_t)b*EMB + e) * SEQ + s] = f2bf(acc[m][n][r] + bvv);
        }
      }
    }
  }
}

// ---------------- K3: fused attention, 1024 threads, bit-mask ---------------
// One block per (b, 32-row q-tile). 16 waves: phase1 j-chunks of 128; phase2
// 16 emb cols per wave. E in LDS (XOR swizzle byte ^= (row&7)<<4).
__global__ __launch_bounds__(1024) void k_attn(
    const u16* __restrict__ Qbf, const u16* __restrict__ Kbf,
    const u16* __restrict__ Vtb, const u32* __restrict__ mb,
    float* __restrict__ dout, u16* __restrict__ Obf)
{
  __shared__ u16 Els[32][2048];     // 128 KiB
  __shared__ float red[16][32];
  __shared__ float invs[32];

  int b = blockIdx.y, qt = blockIdx.x, qbase = qt * 32;
  int t = threadIdx.x, wv = t >> 6, lane = t & 63, g4 = lane >> 4, r16 = lane & 15;
  int jb = wv * 128;
  float* attf = dout + OUT0 + (size_t)(b * NQT + qt) * SLOTF;
  const u32* mrow = mb + ((size_t)b * HW + qbase) * 64;   // 64 words/row
  const u16* Qrow = Qbf + ((size_t)b * HW + qbase) * EMB;
  const u16* Krow = Kbf + (size_t)b * SEQ * EMB;

  float rs[2][4] = {};
  const float SC = 0.0625f;  // EMB^-0.5
  #pragma unroll
  for (int nch = 0; nch < 2; nch++) {
    int jbase = jb + nch * 64;
    uint2 mw[2][4];
    #pragma unroll
    for (int m = 0; m < 2; m++)
      #pragma unroll
      for (int r = 0; r < 4; r++)
        mw[m][r] = *(const uint2*)(mrow + (size_t)(m*16 + g4*4 + r) * 64 + (jbase >> 5));
    f32x4 acc[2][4] = {};
    #pragma unroll
    for (int kk = 0; kk < 8; kk++) {
      bf16x8 kf[4];
      #pragma unroll
      for (int n = 0; n < 4; n++)
        kf[n] = ld16(Krow + (size_t)(jbase + n*16 + r16) * EMB + kk*32 + g4*8);
      bf16x8 q0 = ld16(Qrow + (size_t)(r16) * EMB + kk*32 + g4*8);
      bf16x8 q1 = ld16(Qrow + (size_t)(16 + r16) * EMB + kk*32 + g4*8);
      #pragma unroll
      for (int n = 0; n < 4; n++) {
        acc[0][n] = MFMA(q0, kf[n], acc[0][n]);
        acc[1][n] = MFMA(q1, kf[n], acc[1][n]);
      }
    }
    #pragma unroll
    for (int m = 0; m < 2; m++) {
      int li0 = m*16 + g4*4;
      #pragma unroll
      for (int n = 0; n < 4; n++) {
        int j = jbase + n*16 + r16;
        #pragma unroll
        for (int r = 0; r < 4; r++) {
          u32 wbits = (n < 2) ? mw[m][r].x : mw[m][r].y;
          u32 mk = (wbits >> ((n & 1) * 16 + r16)) & 1u;
          float s = acc[m][n][r] * SC;
          float e = mk ? 0.f : __expf(s);
          rs[m][r] += e;
          int row = li0 + r;
          u32 bo = (u32)(j * 2) ^ ((u32)(row & 7) << 4);
          *(u16*)((char*)&Els[row][0] + bo) = f2bf(e);
        }
      }
    }
  }
  // rowsum: 16-lane shuffle reduce, then cross-wave via LDS
  #pragma unroll
  for (int m = 0; m < 2; m++)
    #pragma unroll
    for (int r = 0; r < 4; r++) {
      float v = rs[m][r];
      v += __shfl_xor(v, 1); v += __shfl_xor(v, 2);
      v += __shfl_xor(v, 4); v += __shfl_xor(v, 8);
      if (r16 == 0) red[wv][m*16 + g4*4 + r] = v;
    }
  __syncthreads();
  if (t < 32) {
    float s2 = 0.f;
    #pragma unroll
    for (int w2 = 0; w2 < 16; w2++) s2 += red[w2][t];
    invs[t] = 1.f / s2;
  }
  __syncthreads();

  // ---- phase 2: O = (E*inv) V ----
  int e0 = wv * 16;
  const u16* Vb = Vtb + (size_t)b * EMB * SEQ + (size_t)(e0 + r16) * SEQ;
  const char* E0p = (const char*)&Els[r16][0];
  const char* E1p = (const char*)&Els[16 + r16][0];
  u32 rxor = (u32)(r16 & 7) << 4;
  f32x4 acc2[2] = {};
  #pragma unroll 4
  for (int kk = 0; kk < 64; kk++) {
    int ko = kk*32 + g4*8;
    u32 bo = (u32)(ko * 2) ^ rxor;
    bf16x8 a0 = __builtin_bit_cast(bf16x8, *(const uint4*)(E0p + bo));
    bf16x8 a1 = __builtin_bit_cast(bf16x8, *(const uint4*)(E1p + bo));
    bf16x8 b0 = ld16(Vb + ko);
    acc2[0] = MFMA(a0, b0, acc2[0]);
    acc2[1] = MFMA(a1, b0, acc2[1]);
  }
  #pragma unroll
  for (int m = 0; m < 2; m++)
    #pragma unroll
    for (int r = 0; r < 4; r++) {
      int li = m*16 + g4*4 + r;
      Obf[((size_t)b*HW + qbase + li) * EMB + e0 + r16] = f2bf(acc2[m][r] * invs[li]);
    }

  // ---- att = E*inv, float4 stores ----
  int arow = t >> 5;                  // 0..31
  int ac = (t & 31) * 4;              // col offset within 128-chunk
  float ivA = invs[arow];
  const char* ErowA = (const char*)&Els[arow][0];
  u32 axor = (u32)(arow & 7) << 4;
  float* attr = attf + (size_t)arow * 2048;
  #pragma unroll 2
  for (int it = 0; it < 16; it++) {
    int col = it * 128 + ac;
    uint2 raw = *(const uint2*)(ErowA + ((u32)(col * 2) ^ axor));
    float4 o;
    o.x = bf2f(raw.x & 0xffffu) * ivA;
    o.y = bf2f(raw.x >> 16) * ivA;
    o.z = bf2f(raw.y & 0xffffu) * ivA;
    o.w = bf2f(raw.y >> 16) * ivA;
    *(float4*)(attr + col) = o;
  }
}

// ---------------- K4: out projection ----------------------------------------
__global__ __launch_bounds__(256) void k_outproj(
    const u16* __restrict__ Obf, const u16* __restrict__ WoutBf,
    const float* __restrict__ bout, float* __restrict__ out)
{
  int b = blockIdx.y, ibase = blockIdx.x * 64;
  int t = threadIdx.x, wv = t >> 6, lane = t & 63, g4 = lane >> 4, r16 = lane & 15;
  int c0 = wv * 64;
  f32x4 acc[4][4] = {};
  #pragma unroll 2
  for (int kk = 0; kk < 8; kk++) {
    bf16x8 a[4];
    #pragma unroll
    for (int m = 0; m < 4; m++)
      a[m] = ld16(WoutBf + (size_t)(c0 + m*16 + r16) * 256 + kk*32 + g4*8);
    bf16x8 bb[4];
    #pragma unroll
    for (int n = 0; n < 4; n++)
      bb[n] = ld16(Obf + ((size_t)b*HW + ibase + n*16 + r16) * EMB + kk*32 + g4*8);
    #pragma unroll
    for (int m = 0; m < 4; m++)
      #pragma unroll
      for (int n = 0; n < 4; n++)
        acc[m][n] = MFMA(a[m], bb[n], acc[m][n]);
  }
  #pragma unroll
  for (int m = 0; m < 4; m++) {
    #pragma unroll
    for (int r = 0; r < 4; r++) {
      int c = c0 + m*16 + g4*4 + r;
      float bo = bout[c];
      #pragma unroll
      for (int n = 0; n < 4; n++) {
        int i = ibase + n*16 + r16;
        out[((size_t)b*CH + c) * HW + i] = acc[m][n][r] + bo;
      }
    }
  }
}

// ---------------- host ------------------------------------------------------
extern "C" void kernel_launch(void* const* d_in, const int* in_sizes, int n_in,
                              void* d_out, int out_size, void* d_ws, size_t ws_size,
                              hipStream_t stream)
{
  const float* x    = (const float*)d_in[0];
  const float* ctx  = (const float*)d_in[1];
  const int*   mask = (const int*)  d_in[2];
  const float* W_in = (const float*)d_in[3];
  const float* b_in = (const float*)d_in[4];
  const float* Wq   = (const float*)d_in[5];
  const float* bq   = (const float*)d_in[6];
  const float* Wk   = (const float*)d_in[7];
  const float* bk   = (const float*)d_in[8];
  const float* Wv   = (const float*)d_in[9];
  const float* bv   = (const float*)d_in[10];
  const float* Wout = (const float*)d_in[11];
  const float* bout = (const float*)d_in[12];
  float* out = (float*)d_out;

  char* ws = (char*)d_ws;
  size_t off = 0;
  auto alloc = [&](size_t bytes) -> void* {
    void* p = ws + off;
    off += (bytes + 255) & ~(size_t)255;
    return p;
  };
  u16*   WqinBf = (u16*)  alloc(256*256*2);
  u16*   WkBf   = (u16*)  alloc(256*128*2);
  u16*   WvBf   = (u16*)  alloc(256*128*2);
  u16*   WoutBf = (u16*)  alloc(256*256*2);
  float* bq_eff = (float*)alloc(256*4);
  u64*   mbits  = (u64*)  alloc((size_t)NMASKW*8);
  u16*   Qbf    = (u16*)  alloc((size_t)BB*HW*EMB*2);   // reused as O by k_attn
  u16*   Kbf    = (u16*)  alloc((size_t)BB*SEQ*EMB*2);
  u16*   Vtb    = (u16*)  alloc((size_t)BB*EMB*SEQ*2);
  if (off > ws_size) return;  // diagnostic bail

  k_prep<<<dim3(320), dim3(256), 0, stream>>>(Wq, W_in, b_in, bq, Wk, Wv, Wout,
                                              WqinBf, WkBf, WvBf, WoutBf, bq_eff);
  k_maskpack<<<dim3(2048), dim3(256), 0, stream>>>(mask, mbits);
  k_qproj<<<dim3(36, 16), dim3(256), 0, stream>>>(x, WqinBf, bq_eff, Qbf);
  k_kvproj<<<dim3(32, 16), dim3(512), 0, stream>>>(ctx, WkBf, WvBf, bk, bv, Kbf, Vtb);
  k_attn<<<dim3(NQT, 16), dim3(1024), 0, stream>>>(Qbf, Kbf, Vtb, (const u32*)mbits,
                                                   out, Qbf /*O*/);
  k_outproj<<<dim3(36, 16), dim3(256), 0, stream>>>(Qbf /*O*/, WoutBf, bout, out);
}